// Round 13
// baseline (174.494 us; speedup 1.0000x reference)
//
#include <hip/hip_runtime.h>
#include <hip/hip_bf16.h>
#include <math.h>

// SpaTrans on MI355X. R13: R12 + head-interleave done right.
// R11 proved the allocator spills rather than drop below 8 waves/EU
// (VGPR=64 + 22MB scratch traffic). amdgpu_waves_per_eu(2,4) lowers the
// occupancy target so Sc[2][10] + dual chains fit in ~110 regs, spill-free.
#define Lh 32
#define Lw 32
#define LL 1024
#define BN 25
#define EE 128
#define CC 64
#define NHD 8
#define DH 16
#define FFD 256
#define MROWS 25600

typedef __attribute__((ext_vector_type(8))) short short8;
typedef __attribute__((ext_vector_type(4))) float f32x4;

__device__ inline ushort f2b(float x) {
    union { float f; unsigned u; } v; v.f = x;
    unsigned r = (v.u + 0x7fffu + ((v.u >> 16) & 1u)) >> 16;
    return (ushort)r;
}
__device__ inline unsigned pk2(float a, float b) {   // packed RNE f32x2 -> bf16x2
    union { __hip_bfloat162 h; unsigned u; } c;
    c.h = __float22bfloat162_rn(make_float2(a, b));
    return c.u;
}
__device__ inline float b2f(ushort u) {
    union { unsigned u; float f; } v; v.u = ((unsigned)u) << 16;
    return v.f;
}

// ---------------------------------------------------------------------------
// Weight layout (ushorts). W2 K-reordered (k'=tap*64+ch). WO/W2F/WC k-PERMUTED
// (kpos=c*32+q*8+i <-> orig k=(2c+(i>>2))*16+q*4+(i&3)). Q rows pre-scaled 0.25.
// ---------------------------------------------------------------------------
#define OFF_W2  0
#define OFF_WQK 73728
#define OFF_WV  106496
#define OFF_WO  122880
#define OFF_W1  139264
#define OFF_W2F 172032
#define OFF_WC  204800
#define W_TOTAL 212992

__global__ __launch_bounds__(256) void k_prep(
    const float* __restrict__ w_mlp, const float* __restrict__ in_proj,
    const float* __restrict__ out_proj, const float* __restrict__ ff_w1,
    const float* __restrict__ ff_w2, const float* __restrict__ conv_w,
    ushort* __restrict__ Wb)
{
    int i = blockIdx.x * 256 + threadIdx.x;
    if (i >= W_TOTAL) return;
    if (i < 73728) {
        int e = i / 576, k = i - e * 576;
        int tap = k >> 6, ch = k & 63;
        Wb[OFF_W2 + i] = f2b(w_mlp[e * 576 + ch * 9 + tap]);
        return;
    }
    i -= 73728;
    if (i < 32768) {   // WQK; Q rows pre-scaled by 1/sqrt(16)
        float v = in_proj[i];
        Wb[OFF_WQK + i] = f2b(i < 16384 ? v * 0.25f : v);
        return;
    }
    i -= 32768;
    if (i < 16384) { Wb[OFF_WV + i] = f2b(in_proj[32768 + i]); return; }
    i -= 16384;
    if (i < 16384) {   // WO, k-permuted (K=128)
        int e = i >> 7, kpos = i & 127;
        int c = kpos >> 5, q = (kpos >> 3) & 3, ii = kpos & 7;
        int orig = (2 * c + (ii >> 2)) * 16 + q * 4 + (ii & 3);
        Wb[OFF_WO + i] = f2b(out_proj[e * 128 + orig]);
        return;
    }
    i -= 16384;
    if (i < 32768) { Wb[OFF_W1 + i] = f2b(ff_w1[i]); return; }
    i -= 32768;
    if (i < 32768) {   // W2F, k-permuted (K=256)
        int e = i >> 8, kpos = i & 255;
        int c = kpos >> 5, q = (kpos >> 3) & 3, ii = kpos & 7;
        int orig = (2 * c + (ii >> 2)) * 16 + q * 4 + (ii & 3);
        Wb[OFF_W2F + i] = f2b(ff_w2[e * 256 + orig]);
        return;
    }
    i -= 32768;
    {                  // WC, k-permuted (K=128)
        int o = i >> 7, kpos = i & 127;
        int c = kpos >> 5, q = (kpos >> 3) & 3, ii = kpos & 7;
        int orig = (2 * c + (ii >> 2)) * 16 + q * 4 + (ii & 3);
        Wb[OFF_WC + i] = f2b(conv_w[o * 128 + orig]);
    }
}

// ---------------------------------------------------------------------------
// Token embed + LN1 + QKV, input transpose fused. Grid 800, XCD-swizzled.
// ---------------------------------------------------------------------------
__global__ __launch_bounds__(256, 3) void k_tok_qkv(
    const float* __restrict__ buf, const float* __restrict__ spa,
    const ushort* __restrict__ W2, const ushort* __restrict__ WQK,
    const ushort* __restrict__ WV, const float* __restrict__ g1,
    const float* __restrict__ b1, ushort* __restrict__ TOKb,
    ushort* __restrict__ Qh, ushort* __restrict__ Kh, ushort* __restrict__ VTg)
{
    const int bid = blockIdx.x;                       // 800 blocks
    const int idx = (bid & 7) * 100 + (bid >> 3);     // XCD-contiguous chunks
    const int n = idx / 32, y = idx & 31;
    __shared__ ushort At[3 * 34 * 72];
    __shared__ ushort As_[3 * 34 * 72];
    __shared__ ushort Xs[32 * 136];   // phase A: aliased as t0 (fp32 [64][33])
    __shared__ ushort Vs[32 * 136];   // phase A: aliased as t1
    __shared__ float2 red[32][4];
    float* t0 = (float*)Xs;
    float* t1 = (float*)Vs;
    const int t = threadIdx.x;
    const uint4 z = make_uint4(0, 0, 0, 0);

    // ---- fused input transpose: 3 rows (y-1, y, y+1) ----
    for (int dy = 0; dy < 3; dy++) {
        int yy = y + dy - 1;
        if (yy >= 0 && yy < Lh) {
            {
                int ch = t >> 2, x8 = (t & 3) * 8;
                const float* p = buf + ((size_t)(ch * BN + n) * LL + yy * Lw + x8);
                const float* q = spa + ((size_t)(ch * BN + n) * LL + yy * Lw + x8);
                float4 a0 = ((const float4*)p)[0], a1 = ((const float4*)p)[1];
                float4 b0 = ((const float4*)q)[0], b1 = ((const float4*)q)[1];
                float* d0 = t0 + ch * 33 + x8;
                float* d1 = t1 + ch * 33 + x8;
                d0[0] = a0.x; d0[1] = a0.y; d0[2] = a0.z; d0[3] = a0.w;
                d0[4] = a1.x; d0[5] = a1.y; d0[6] = a1.z; d0[7] = a1.w;
                d1[0] = a0.x + b0.x; d1[1] = a0.y + b0.y; d1[2] = a0.z + b0.z; d1[3] = a0.w + b0.w;
                d1[4] = a1.x + b1.x; d1[5] = a1.y + b1.y; d1[6] = a1.z + b1.z; d1[7] = a1.w + b1.w;
            }
            __syncthreads();
            {
                int x = t >> 3, c8 = (t & 7) * 8;
                union { unsigned u[4]; uint4 v; } o0, o1;
#pragma unroll
                for (int j = 0; j < 4; j++) {
                    o0.u[j] = pk2(t0[(c8 + 2 * j) * 33 + x], t0[(c8 + 2 * j + 1) * 33 + x]);
                    o1.u[j] = pk2(t1[(c8 + 2 * j) * 33 + x], t1[(c8 + 2 * j + 1) * 33 + x]);
                }
                *(uint4*)(At + (dy * 34 + x + 1) * 72 + c8) = o0.v;
                *(uint4*)(As_ + (dy * 34 + x + 1) * 72 + c8) = o1.v;
            }
            __syncthreads();
        } else {
            int x = t >> 3, c8 = (t & 7) * 8;
            *(uint4*)(At + (dy * 34 + x + 1) * 72 + c8) = z;
            *(uint4*)(As_ + (dy * 34 + x + 1) * 72 + c8) = z;
        }
    }
    if (t < 48) {   // zero pad columns (x=-1 and x=32)
        int dy = t / 16, rem = t % 16;
        int colp = (rem >> 3) * 33, c8p = (rem & 7) * 8;
        *(uint4*)(At + (dy * 34 + colp) * 72 + c8p) = z;
        *(uint4*)(As_ + (dy * 34 + colp) * 72 + c8p) = z;
    }
    __syncthreads();

    const int w = t >> 6, lane = t & 63;
    const int col = lane & 15, quad = lane >> 4;
    f32x4 accT[2][2] = {}, accS[2][2] = {};

    for (int tap = 0; tap < 9; tap++) {
        int dy = tap / 3, dx = tap % 3;
#pragma unroll
        for (int cc = 0; cc < 2; cc++) {
            int kg = tap * 64 + cc * 32 + quad * 8;
            short8 b0 = *(const short8*)(W2 + (size_t)(w * 32 + col) * 576 + kg);
            short8 bq = *(const short8*)(W2 + (size_t)(w * 32 + 16 + col) * 576 + kg);
            int abase = (dy * 34 + col + dx) * 72 + cc * 32 + quad * 8;
            short8 aT0 = *(const short8*)(At + abase);
            short8 aT1 = *(const short8*)(At + abase + 16 * 72);
            short8 aS0 = *(const short8*)(As_ + abase);
            short8 aS1 = *(const short8*)(As_ + abase + 16 * 72);
            accT[0][0] = __builtin_amdgcn_mfma_f32_16x16x32_bf16(aT0, b0, accT[0][0], 0, 0, 0);
            accT[0][1] = __builtin_amdgcn_mfma_f32_16x16x32_bf16(aT0, bq, accT[0][1], 0, 0, 0);
            accT[1][0] = __builtin_amdgcn_mfma_f32_16x16x32_bf16(aT1, b0, accT[1][0], 0, 0, 0);
            accT[1][1] = __builtin_amdgcn_mfma_f32_16x16x32_bf16(aT1, bq, accT[1][1], 0, 0, 0);
            accS[0][0] = __builtin_amdgcn_mfma_f32_16x16x32_bf16(aS0, b0, accS[0][0], 0, 0, 0);
            accS[0][1] = __builtin_amdgcn_mfma_f32_16x16x32_bf16(aS0, bq, accS[0][1], 0, 0, 0);
            accS[1][0] = __builtin_amdgcn_mfma_f32_16x16x32_bf16(aS1, b0, accS[1][0], 0, 0, 0);
            accS[1][1] = __builtin_amdgcn_mfma_f32_16x16x32_bf16(aS1, bq, accS[1][1], 0, 0, 0);
        }
    }

    // LN1 partial sums
#pragma unroll
    for (int mi = 0; mi < 2; mi++)
#pragma unroll
        for (int r = 0; r < 4; r++) {
            float a0 = accS[mi][0][r], a1 = accS[mi][1][r];
            float ss = a0 + a1, qq = a0 * a0 + a1 * a1;
#pragma unroll
            for (int m = 1; m < 16; m <<= 1) {
                ss += __shfl_xor(ss, m, 64);
                qq += __shfl_xor(qq, m, 64);
            }
            if (col == 0) red[mi * 16 + quad * 4 + r][w] = make_float2(ss, qq);
        }
    __syncthreads();

    const float ga = g1[w * 32 + col],      ba = b1[w * 32 + col];
    const float gb = g1[w * 32 + 16 + col], bb = b1[w * 32 + 16 + col];
#pragma unroll
    for (int mi = 0; mi < 2; mi++)
#pragma unroll
        for (int r = 0; r < 4; r++) {
            int x = mi * 16 + quad * 4 + r;
            float2 p0 = red[x][0], p1 = red[x][1], p2 = red[x][2], p3 = red[x][3];
            float mean = (p0.x + p1.x + p2.x + p3.x) * (1.f / 128.f);
            float var  = (p0.y + p1.y + p2.y + p3.y) * (1.f / 128.f) - mean * mean;
            float rstd = rsqrtf(var + 1e-5f);
            int e0 = w * 32 + col, e1 = w * 32 + 16 + col;
            Xs[x * 136 + e0] = f2b((accS[mi][0][r] - mean) * rstd * ga + ba);
            Xs[x * 136 + e1] = f2b((accS[mi][1][r] - mean) * rstd * gb + bb);
            Vs[x * 136 + e0] = f2b(accT[mi][0][r]);
            Vs[x * 136 + e1] = f2b(accT[mi][1][r]);
        }
    __syncthreads();

    // phase B: QKV. Wave w -> heads 2w, 2w+1; token tiles j=0,1.
    short8 xb[2][4], xv[2][4];
#pragma unroll
    for (int j = 0; j < 2; j++)
#pragma unroll
        for (int kc = 0; kc < 4; kc++) {
            xb[j][kc] = *(const short8*)(Xs + (j * 16 + col) * 136 + kc * 32 + quad * 8);
            xv[j][kc] = *(const short8*)(Vs + (j * 16 + col) * 136 + kc * 32 + quad * 8);
        }
    f32x4 Q[2][2] = {}, K[2][2] = {}, V[2][2] = {};
#pragma unroll
    for (int hj = 0; hj < 2; hj++) {
        int h = 2 * w + hj;
#pragma unroll
        for (int kc = 0; kc < 4; kc++) {
            short8 aq = *(const short8*)(WQK + (size_t)(h * 16 + col) * 128 + kc * 32 + quad * 8);
            short8 ak = *(const short8*)(WQK + (size_t)(128 + h * 16 + col) * 128 + kc * 32 + quad * 8);
            short8 av = *(const short8*)(WV + (size_t)(h * 16 + col) * 128 + kc * 32 + quad * 8);
#pragma unroll
            for (int j = 0; j < 2; j++) {
                Q[hj][j] = __builtin_amdgcn_mfma_f32_16x16x32_bf16(aq, xb[j][kc], Q[hj][j], 0, 0, 0);
                K[hj][j] = __builtin_amdgcn_mfma_f32_16x16x32_bf16(ak, xb[j][kc], K[hj][j], 0, 0, 0);
                V[hj][j] = __builtin_amdgcn_mfma_f32_16x16x32_bf16(av, xv[j][kc], V[hj][j], 0, 0, 0);
            }
        }
    }
    ushort* VTs = At;   // dead after MFMA loop; [8 heads][16 d][stride 34]
#pragma unroll
    for (int hj = 0; hj < 2; hj++) {
        int h = 2 * w + hj;
#pragma unroll
        for (int j = 0; j < 2; j++) {
            int l = y * 32 + j * 16 + col;
            size_t base = ((size_t)(n * 8 + h) * 1024 + l) * 16 + quad * 4;
            union { unsigned u[2]; uint2 v; } oq, ok;
            oq.u[0] = pk2(Q[hj][j][0], Q[hj][j][1]); oq.u[1] = pk2(Q[hj][j][2], Q[hj][j][3]);
            ok.u[0] = pk2(K[hj][j][0], K[hj][j][1]); ok.u[1] = pk2(K[hj][j][2], K[hj][j][3]);
            *(uint2*)(Qh + base) = oq.v;
            *(uint2*)(Kh + base) = ok.v;
            int xp = ((col >> 2) << 3) + (j << 2) + (col & 3);
#pragma unroll
            for (int r = 0; r < 4; r++)
                VTs[(h * 16 + quad * 4 + r) * 34 + xp] = f2b(V[hj][j][r]);
        }
    }
#pragma unroll
    for (int k = 0; k < 2; k++) {
        int idx2 = t + k * 256;
        int r = idx2 >> 4, seg = idx2 & 15;
        *(uint4*)(TOKb + ((size_t)((y * 32 + r) * 25 + n)) * 128 + seg * 8) =
            *(const uint4*)(Vs + r * 136 + seg * 8);
    }
    __syncthreads();
    {   // coalesced VTg write
        int h = t >> 5, rem = t & 31, d = rem >> 1, xh = (rem & 1) * 16;
        size_t vrow = ((size_t)(n * 8 + h) * 32 + y) * 512;
        union { ushort u[8]; uint4 v; } o0, o1;
#pragma unroll
        for (int j = 0; j < 8; j++) {
            o0.u[j] = VTs[(h * 16 + d) * 34 + xh + j];
            o1.u[j] = VTs[(h * 16 + d) * 34 + xh + 8 + j];
        }
        *(uint4*)(VTg + vrow + d * 32 + xh)     = o0.v;
        *(uint4*)(VTg + vrow + d * 32 + xh + 8) = o1.v;
    }
}

// ---------------------------------------------------------------------------
// Attention + out_proj + residual + LN2 + FFN + conv, fully fused.
// Grid 1600 (n,y,half). Heads INTERLEAVED with waves_per_eu(2,4) so the
// allocator keeps Sc[2][10] + dual chains in regs (R11 spilled at the
// default 8-wave target). No-max softmax; Ys on Rs; pk2 packs.
// ---------------------------------------------------------------------------
__global__ __launch_bounds__(256)
__attribute__((amdgpu_waves_per_eu(2, 4)))
void k_attn_ffn(
    const ushort* __restrict__ Qh, const ushort* __restrict__ Kh,
    const ushort* __restrict__ VTg, const ushort* __restrict__ WOP,
    const float* __restrict__ g2, const float* __restrict__ b2,
    const ushort* __restrict__ W1, const ushort* __restrict__ W2P,
    const ushort* __restrict__ WCP, const ushort* __restrict__ TOKb,
    float* __restrict__ out)
{
    __shared__ ushort OX[16 * 136];
    __shared__ ushort Rs[16 * 136];   // residual; later aliased as Ys
    __shared__ ushort Hs[16 * 264];
    __shared__ float2 red[16][4];
    ushort* Ys = Rs;                  // Rs dead 3 barriers before Ys write
    const int bid = blockIdx.x;                       // 1600 blocks
    const int idx = (bid & 7) * 200 + (bid >> 3);     // XCD-contiguous chunks
    const int n = idx / 64, rem = idx & 63;
    const int y = rem >> 1, half = rem & 1;
    const int l0 = y * 32 + half * 16;
    const int t = threadIdx.x, w = t >> 6, lane = t & 63;
    const int col = lane & 15, quad = lane >> 4;
    const int qx = half * 16 + col;

    {   // stage residual rows (16 tokens, bf16)
        int r = t >> 4, seg = t & 15;
        *(uint4*)(Rs + r * 136 + seg * 8) =
            *(const uint4*)(TOKb + ((size_t)((l0 + r) * 25 + n)) * 128 + seg * 8);
    }

    // hoisted mask bits (head-independent)
    unsigned long long mbits = 0;
#pragma unroll
    for (int tt = 0; tt < 10; tt++) {
        int yy = y - 2 + (tt >> 1);
        bool rok = (yy >= 0) && (yy < 32);
        int kxb = ((tt & 1) << 4) + quad * 4;
#pragma unroll
        for (int r = 0; r < 4; r++) {
            int dd = kxb + r - qx;
            if (rok && ((unsigned)(dd + 2) <= 4u))
                mbits |= 1ull << (tt * 4 + r);
        }
    }

    short8 z8 = {0, 0, 0, 0, 0, 0, 0, 0};
    const size_t base0 = (size_t)(n * 8 + 2 * w) * 1024;
    const size_t base1 = base0 + 1024;
    const size_t vbase0 = (size_t)(n * 8 + 2 * w) * 32 * 512;
    const size_t vbase1 = vbase0 + 32 * 512;

    short8 qf0 = z8, qf1 = z8;
    if (quad < 2) {
        qf0 = *(const short8*)(Qh + (base0 + y * 32 + half * 16 + col) * 16 + quad * 8);
        qf1 = *(const short8*)(Qh + (base1 + y * 32 + half * 16 + col) * 16 + quad * 8);
    }

    // scores, both heads interleaved
    f32x4 Sc[2][10] = {};
#pragma unroll
    for (int tt = 0; tt < 10; tt++) {
        int kr = tt >> 1, kx = ((tt & 1) << 4) + col;
        int yyc = min(max(y - 2 + kr, 0), 31);
        short8 kf0 = z8, kf1 = z8;
        if (quad < 2) {
            kf0 = *(const short8*)(Kh + (base0 + yyc * 32 + kx) * 16 + quad * 8);
            kf1 = *(const short8*)(Kh + (base1 + yyc * 32 + kx) * 16 + quad * 8);
        }
        Sc[0][tt] = __builtin_amdgcn_mfma_f32_16x16x32_bf16(kf0, qf0, Sc[0][tt], 0, 0, 0);
        Sc[1][tt] = __builtin_amdgcn_mfma_f32_16x16x32_bf16(kf1, qf1, Sc[1][tt], 0, 0, 0);
    }

    // softmax WITHOUT max-subtraction (|S| ~ 0.05; shift-invariant)
    float sum0 = 0.f, sum1 = 0.f;
#pragma unroll
    for (int tt = 0; tt < 10; tt++)
#pragma unroll
        for (int r = 0; r < 4; r++) {
            bool ok = (mbits >> (tt * 4 + r)) & 1;
            float p0 = ok ? __expf(Sc[0][tt][r]) : 0.f;
            float p1 = ok ? __expf(Sc[1][tt][r]) : 0.f;
            Sc[0][tt][r] = p0; Sc[1][tt][r] = p1;
            sum0 += p0; sum1 += p1;
        }
    sum0 += __shfl_xor(sum0, 16, 64); sum0 += __shfl_xor(sum0, 32, 64);
    sum1 += __shfl_xor(sum1, 16, 64); sum1 += __shfl_xor(sum1, 32, 64);
    const float inv0 = 1.f / sum0, inv1 = 1.f / sum1;

    // PV interleaved: A-frags from VTg; P packed UNNORMALIZED (pk2)
    f32x4 O20 = {}, O21 = {};
#pragma unroll
    for (int c = 0; c < 5; c++) {
        int yyc = min(max(y - 2 + c, 0), 31);
        short8 vt0 = *(const short8*)(VTg + vbase0 + (size_t)yyc * 512 + col * 32 + quad * 8);
        short8 vt1 = *(const short8*)(VTg + vbase1 + (size_t)yyc * 512 + col * 32 + quad * 8);
        union { unsigned u[4]; short8 s; } pb0, pb1;
        pb0.u[0] = pk2(Sc[0][2 * c][0], Sc[0][2 * c][1]);
        pb0.u[1] = pk2(Sc[0][2 * c][2], Sc[0][2 * c][3]);
        pb0.u[2] = pk2(Sc[0][2 * c + 1][0], Sc[0][2 * c + 1][1]);
        pb0.u[3] = pk2(Sc[0][2 * c + 1][2], Sc[0][2 * c + 1][3]);
        pb1.u[0] = pk2(Sc[1][2 * c][0], Sc[1][2 * c][1]);
        pb1.u[1] = pk2(Sc[1][2 * c][2], Sc[1][2 * c][3]);
        pb1.u[2] = pk2(Sc[1][2 * c + 1][0], Sc[1][2 * c + 1][1]);
        pb1.u[3] = pk2(Sc[1][2 * c + 1][2], Sc[1][2 * c + 1][3]);
        O20 = __builtin_amdgcn_mfma_f32_16x16x32_bf16(vt0, pb0.s, O20, 0, 0, 0);
        O21 = __builtin_amdgcn_mfma_f32_16x16x32_bf16(vt1, pb1.s, O21, 0, 0, 0);
    }
#pragma unroll
    for (int r = 0; r < 4; r++) { O20[r] *= inv0; O21[r] *= inv1; }

    // pack O (heads 2w,2w+1) -> OX as B-operand k-slice w
    {
        union { unsigned u[4]; uint4 v; } pb;
        pb.u[0] = pk2(O20[0], O20[1]); pb.u[1] = pk2(O20[2], O20[3]);
        pb.u[2] = pk2(O21[0], O21[1]); pb.u[3] = pk2(O21[2], O21[3]);
        *(uint4*)(OX + col * 136 + w * 32 + quad * 8) = pb.v;
    }
    __syncthreads();

    // out_proj: wave w -> e-tiles {2w, 2w+1}
    f32x4 Y[2] = {};
#pragma unroll
    for (int kc = 0; kc < 4; kc++) {
        short8 hb = *(const short8*)(OX + col * 136 + kc * 32 + quad * 8);
#pragma unroll
        for (int jj = 0; jj < 2; jj++) {
            int et = 2 * w + jj;
            short8 a = *(const short8*)(WOP + (size_t)(et * 16 + col) * 128 + kc * 32 + quad * 8);
            Y[jj] = __builtin_amdgcn_mfma_f32_16x16x32_bf16(a, hb, Y[jj], 0, 0, 0);
        }
    }
    // residual + LN2 stats (token = col); tok2 stays in Y[] registers
    float sum = 0.f, sq = 0.f;
#pragma unroll
    for (int jj = 0; jj < 2; jj++)
#pragma unroll
        for (int r = 0; r < 4; r++) {
            int e = (2 * w + jj) * 16 + quad * 4 + r;
            float v = Y[jj][r] + b2f(Rs[col * 136 + e]);
            Y[jj][r] = v;
            sum += v; sq += v * v;
        }
    sum += __shfl_xor(sum, 16, 64); sum += __shfl_xor(sum, 32, 64);
    sq  += __shfl_xor(sq, 16, 64);  sq  += __shfl_xor(sq, 32, 64);
    if (quad == 0) red[col][w] = make_float2(sum, sq);
    __syncthreads();

    {
        float2 p0 = red[col][0], p1 = red[col][1], p2 = red[col][2], p3 = red[col][3];
        float mean = (p0.x + p1.x + p2.x + p3.x) * (1.f / 128.f);
        float var  = (p0.y + p1.y + p2.y + p3.y) * (1.f / 128.f) - mean * mean;
        float rstd = rsqrtf(var + 1e-5f);
#pragma unroll
        for (int jj = 0; jj < 2; jj++)
#pragma unroll
            for (int r2 = 0; r2 < 4; r2 += 2) {
                int e = (2 * w + jj) * 16 + quad * 4 + r2;
                float v0 = (Y[jj][r2]     - mean) * rstd * g2[e]     + b2[e];
                float v1 = (Y[jj][r2 + 1] - mean) * rstd * g2[e + 1] + b2[e + 1];
                *(unsigned*)(OX + col * 136 + e) = pk2(v0, v1);
            }
    }
    __syncthreads();

    // ffn phase 1: ft = 4w..4w+3 over K=128 from OX
    short8 xb[4];
#pragma unroll
    for (int kc = 0; kc < 4; kc++)
        xb[kc] = *(const short8*)(OX + col * 136 + kc * 32 + quad * 8);
    f32x4 H[4] = {};
#pragma unroll
    for (int j = 0; j < 4; j++) {
        int ft = 4 * w + j;
#pragma unroll
        for (int kc = 0; kc < 4; kc++) {
            short8 a = *(const short8*)(W1 + (size_t)(ft * 16 + col) * 128 + kc * 32 + quad * 8);
            H[j] = __builtin_amdgcn_mfma_f32_16x16x32_bf16(a, xb[kc], H[j], 0, 0, 0);
        }
    }
#pragma unroll
    for (int cc = 0; cc < 2; cc++) {
        union { unsigned u[4]; uint4 v; } pb;
        pb.u[0] = pk2(fmaxf(H[2 * cc][0], 0.f), fmaxf(H[2 * cc][1], 0.f));
        pb.u[1] = pk2(fmaxf(H[2 * cc][2], 0.f), fmaxf(H[2 * cc][3], 0.f));
        pb.u[2] = pk2(fmaxf(H[2 * cc + 1][0], 0.f), fmaxf(H[2 * cc + 1][1], 0.f));
        pb.u[3] = pk2(fmaxf(H[2 * cc + 1][2], 0.f), fmaxf(H[2 * cc + 1][3], 0.f));
        *(uint4*)(Hs + col * 264 + (2 * w + cc) * 32 + quad * 8) = pb.v;
    }
    __syncthreads();

    // ffn phase 2: et = 2w, 2w+1 over K=256; residual from Y[] registers
    f32x4 Y2[2] = {};
#pragma unroll
    for (int kc = 0; kc < 8; kc++) {
        short8 hb = *(const short8*)(Hs + col * 264 + kc * 32 + quad * 8);
#pragma unroll
        for (int j = 0; j < 2; j++) {
            int et = 2 * w + j;
            short8 a = *(const short8*)(W2P + (size_t)(et * 16 + col) * 256 + kc * 32 + quad * 8);
            Y2[j] = __builtin_amdgcn_mfma_f32_16x16x32_bf16(a, hb, Y2[j], 0, 0, 0);
        }
    }
    {
        union { unsigned u[4]; uint4 v; } pb;
        pb.u[0] = pk2(Y2[0][0] + Y[0][0], Y2[0][1] + Y[0][1]);
        pb.u[1] = pk2(Y2[0][2] + Y[0][2], Y2[0][3] + Y[0][3]);
        pb.u[2] = pk2(Y2[1][0] + Y[1][0], Y2[1][1] + Y[1][1]);
        pb.u[3] = pk2(Y2[1][2] + Y[1][2], Y2[1][3] + Y[1][3]);
        *(uint4*)(Ys + col * 136 + w * 32 + quad * 8) = pb.v;
    }
    __syncthreads();

    // ffn phase 3: conv, ot = w
    f32x4 O = {};
#pragma unroll
    for (int c = 0; c < 4; c++) {
        short8 yb = *(const short8*)(Ys + col * 136 + c * 32 + quad * 8);
        short8 a = *(const short8*)(WCP + (size_t)(w * 16 + col) * 128 + c * 32 + quad * 8);
        O = __builtin_amdgcn_mfma_f32_16x16x32_bf16(a, yb, O, 0, 0, 0);
    }
    const int l = l0 + col;
#pragma unroll
    for (int r2 = 0; r2 < 4; r2++) {
        int o = w * 16 + quad * 4 + r2;
        out[(size_t)(o * 25 + n) * 1024 + l] = O[r2];
    }
}

// ---------------------------------------------------------------------------
// Launch
// ---------------------------------------------------------------------------
extern "C" void kernel_launch(void* const* d_in, const int* in_sizes, int n_in,
                              void* d_out, int out_size, void* d_ws, size_t ws_size,
                              hipStream_t stream)
{
    const float* buffer   = (const float*)d_in[0];
    const float* spa      = (const float*)d_in[1];
    const float* w_mlp    = (const float*)d_in[2];
    const float* ln1_g    = (const float*)d_in[3];
    const float* ln1_b    = (const float*)d_in[4];
    const float* in_proj  = (const float*)d_in[5];
    const float* out_proj = (const float*)d_in[6];
    const float* ln2_g    = (const float*)d_in[7];
    const float* ln2_b    = (const float*)d_in[8];
    const float* ff_w1    = (const float*)d_in[9];
    const float* ff_w2    = (const float*)d_in[10];
    const float* conv_w   = (const float*)d_in[11];
    float* out = (float*)d_out;

    char* ws = (char*)d_ws;
    ushort* TOKb = (ushort*)(ws);                //  6,553,600 residual bf16
    ushort* Qh   = (ushort*)(ws + 6553600);      //  6,553,600 [n][h][l][d]
    ushort* Kh   = (ushort*)(ws + 13107200);     //  6,553,600
    ushort* VTg  = (ushort*)(ws + 19660800);     //  6,553,600 [n][h][y][d][xp]
    ushort* Wb   = (ushort*)(ws + 26214400);     //    425,984

    k_prep<<<dim3((W_TOTAL + 255) / 256), 256, 0, stream>>>(
        w_mlp, in_proj, out_proj, ff_w1, ff_w2, conv_w, Wb);
    k_tok_qkv<<<dim3(800), 256, 0, stream>>>(buffer, spa, Wb + OFF_W2,
                                             Wb + OFF_WQK, Wb + OFF_WV,
                                             ln1_g, ln1_b, TOKb, Qh, Kh, VTg);
    k_attn_ffn<<<dim3(1600), 256, 0, stream>>>(Qh, Kh, VTg, Wb + OFF_WO,
                                               ln2_g, ln2_b, Wb + OFF_W1,
                                               Wb + OFF_W2F, Wb + OFF_WC,
                                               TOKb, out);
}

// Round 14
// 173.225 us; speedup vs baseline: 1.0073x; 1.0073x over previous
//
#include <hip/hip_runtime.h>
#include <hip/hip_bf16.h>
#include <math.h>

// SpaTrans on MI355X. R14: k_attn_ffn restructured to 512-thread blocks
// (8 waves, 1 head/wave): per-wave MFMA chain 74 -> ~37, wave count 2x.
// R8/R11/R12/R13 all plateaued at ~55us with 4-wave blocks regardless of
// register strategy -> the bound is chain-length x wave-count, not ILP.
#define Lh 32
#define Lw 32
#define LL 1024
#define BN 25
#define EE 128
#define CC 64
#define NHD 8
#define DH 16
#define FFD 256
#define MROWS 25600

typedef __attribute__((ext_vector_type(8))) short short8;
typedef __attribute__((ext_vector_type(4))) float f32x4;

__device__ inline ushort f2b(float x) {
    union { float f; unsigned u; } v; v.f = x;
    unsigned r = (v.u + 0x7fffu + ((v.u >> 16) & 1u)) >> 16;
    return (ushort)r;
}
__device__ inline unsigned pk2(float a, float b) {   // packed RNE f32x2 -> bf16x2
    union { __hip_bfloat162 h; unsigned u; } c;
    c.h = __float22bfloat162_rn(make_float2(a, b));
    return c.u;
}
__device__ inline float b2f(ushort u) {
    union { unsigned u; float f; } v; v.u = ((unsigned)u) << 16;
    return v.f;
}

// ---------------------------------------------------------------------------
// Weight layout (ushorts). W2 K-reordered (k'=tap*64+ch). WO/W2F/WC k-PERMUTED
// (kpos=c*32+q*8+i <-> orig k=(2c+(i>>2))*16+q*4+(i&3)). Q rows pre-scaled 0.25.
// ---------------------------------------------------------------------------
#define OFF_W2  0
#define OFF_WQK 73728
#define OFF_WV  106496
#define OFF_WO  122880
#define OFF_W1  139264
#define OFF_W2F 172032
#define OFF_WC  204800
#define W_TOTAL 212992

__global__ __launch_bounds__(256) void k_prep(
    const float* __restrict__ w_mlp, const float* __restrict__ in_proj,
    const float* __restrict__ out_proj, const float* __restrict__ ff_w1,
    const float* __restrict__ ff_w2, const float* __restrict__ conv_w,
    ushort* __restrict__ Wb)
{
    int i = blockIdx.x * 256 + threadIdx.x;
    if (i >= W_TOTAL) return;
    if (i < 73728) {
        int e = i / 576, k = i - e * 576;
        int tap = k >> 6, ch = k & 63;
        Wb[OFF_W2 + i] = f2b(w_mlp[e * 576 + ch * 9 + tap]);
        return;
    }
    i -= 73728;
    if (i < 32768) {   // WQK; Q rows pre-scaled by 1/sqrt(16)
        float v = in_proj[i];
        Wb[OFF_WQK + i] = f2b(i < 16384 ? v * 0.25f : v);
        return;
    }
    i -= 32768;
    if (i < 16384) { Wb[OFF_WV + i] = f2b(in_proj[32768 + i]); return; }
    i -= 16384;
    if (i < 16384) {   // WO, k-permuted (K=128)
        int e = i >> 7, kpos = i & 127;
        int c = kpos >> 5, q = (kpos >> 3) & 3, ii = kpos & 7;
        int orig = (2 * c + (ii >> 2)) * 16 + q * 4 + (ii & 3);
        Wb[OFF_WO + i] = f2b(out_proj[e * 128 + orig]);
        return;
    }
    i -= 16384;
    if (i < 32768) { Wb[OFF_W1 + i] = f2b(ff_w1[i]); return; }
    i -= 32768;
    if (i < 32768) {   // W2F, k-permuted (K=256)
        int e = i >> 8, kpos = i & 255;
        int c = kpos >> 5, q = (kpos >> 3) & 3, ii = kpos & 7;
        int orig = (2 * c + (ii >> 2)) * 16 + q * 4 + (ii & 3);
        Wb[OFF_W2F + i] = f2b(ff_w2[e * 256 + orig]);
        return;
    }
    i -= 32768;
    {                  // WC, k-permuted (K=128)
        int o = i >> 7, kpos = i & 127;
        int c = kpos >> 5, q = (kpos >> 3) & 3, ii = kpos & 7;
        int orig = (2 * c + (ii >> 2)) * 16 + q * 4 + (ii & 3);
        Wb[OFF_WC + i] = f2b(conv_w[o * 128 + orig]);
    }
}

// ---------------------------------------------------------------------------
// Token embed + LN1 + QKV, input transpose fused (unchanged from R12).
// ---------------------------------------------------------------------------
__global__ __launch_bounds__(256, 3) void k_tok_qkv(
    const float* __restrict__ buf, const float* __restrict__ spa,
    const ushort* __restrict__ W2, const ushort* __restrict__ WQK,
    const ushort* __restrict__ WV, const float* __restrict__ g1,
    const float* __restrict__ b1, ushort* __restrict__ TOKb,
    ushort* __restrict__ Qh, ushort* __restrict__ Kh, ushort* __restrict__ VTg)
{
    const int bid = blockIdx.x;                       // 800 blocks
    const int idx = (bid & 7) * 100 + (bid >> 3);     // XCD-contiguous chunks
    const int n = idx / 32, y = idx & 31;
    __shared__ ushort At[3 * 34 * 72];
    __shared__ ushort As_[3 * 34 * 72];
    __shared__ ushort Xs[32 * 136];   // phase A: aliased as t0 (fp32 [64][33])
    __shared__ ushort Vs[32 * 136];   // phase A: aliased as t1
    __shared__ float2 red[32][4];
    float* t0 = (float*)Xs;
    float* t1 = (float*)Vs;
    const int t = threadIdx.x;
    const uint4 z = make_uint4(0, 0, 0, 0);

    for (int dy = 0; dy < 3; dy++) {
        int yy = y + dy - 1;
        if (yy >= 0 && yy < Lh) {
            {
                int ch = t >> 2, x8 = (t & 3) * 8;
                const float* p = buf + ((size_t)(ch * BN + n) * LL + yy * Lw + x8);
                const float* q = spa + ((size_t)(ch * BN + n) * LL + yy * Lw + x8);
                float4 a0 = ((const float4*)p)[0], a1 = ((const float4*)p)[1];
                float4 b0 = ((const float4*)q)[0], b1 = ((const float4*)q)[1];
                float* d0 = t0 + ch * 33 + x8;
                float* d1 = t1 + ch * 33 + x8;
                d0[0] = a0.x; d0[1] = a0.y; d0[2] = a0.z; d0[3] = a0.w;
                d0[4] = a1.x; d0[5] = a1.y; d0[6] = a1.z; d0[7] = a1.w;
                d1[0] = a0.x + b0.x; d1[1] = a0.y + b0.y; d1[2] = a0.z + b0.z; d1[3] = a0.w + b0.w;
                d1[4] = a1.x + b1.x; d1[5] = a1.y + b1.y; d1[6] = a1.z + b1.z; d1[7] = a1.w + b1.w;
            }
            __syncthreads();
            {
                int x = t >> 3, c8 = (t & 7) * 8;
                union { unsigned u[4]; uint4 v; } o0, o1;
#pragma unroll
                for (int j = 0; j < 4; j++) {
                    o0.u[j] = pk2(t0[(c8 + 2 * j) * 33 + x], t0[(c8 + 2 * j + 1) * 33 + x]);
                    o1.u[j] = pk2(t1[(c8 + 2 * j) * 33 + x], t1[(c8 + 2 * j + 1) * 33 + x]);
                }
                *(uint4*)(At + (dy * 34 + x + 1) * 72 + c8) = o0.v;
                *(uint4*)(As_ + (dy * 34 + x + 1) * 72 + c8) = o1.v;
            }
            __syncthreads();
        } else {
            int x = t >> 3, c8 = (t & 7) * 8;
            *(uint4*)(At + (dy * 34 + x + 1) * 72 + c8) = z;
            *(uint4*)(As_ + (dy * 34 + x + 1) * 72 + c8) = z;
        }
    }
    if (t < 48) {   // zero pad columns (x=-1 and x=32)
        int dy = t / 16, rem = t % 16;
        int colp = (rem >> 3) * 33, c8p = (rem & 7) * 8;
        *(uint4*)(At + (dy * 34 + colp) * 72 + c8p) = z;
        *(uint4*)(As_ + (dy * 34 + colp) * 72 + c8p) = z;
    }
    __syncthreads();

    const int w = t >> 6, lane = t & 63;
    const int col = lane & 15, quad = lane >> 4;
    f32x4 accT[2][2] = {}, accS[2][2] = {};

    for (int tap = 0; tap < 9; tap++) {
        int dy = tap / 3, dx = tap % 3;
#pragma unroll
        for (int cc = 0; cc < 2; cc++) {
            int kg = tap * 64 + cc * 32 + quad * 8;
            short8 b0 = *(const short8*)(W2 + (size_t)(w * 32 + col) * 576 + kg);
            short8 bq = *(const short8*)(W2 + (size_t)(w * 32 + 16 + col) * 576 + kg);
            int abase = (dy * 34 + col + dx) * 72 + cc * 32 + quad * 8;
            short8 aT0 = *(const short8*)(At + abase);
            short8 aT1 = *(const short8*)(At + abase + 16 * 72);
            short8 aS0 = *(const short8*)(As_ + abase);
            short8 aS1 = *(const short8*)(As_ + abase + 16 * 72);
            accT[0][0] = __builtin_amdgcn_mfma_f32_16x16x32_bf16(aT0, b0, accT[0][0], 0, 0, 0);
            accT[0][1] = __builtin_amdgcn_mfma_f32_16x16x32_bf16(aT0, bq, accT[0][1], 0, 0, 0);
            accT[1][0] = __builtin_amdgcn_mfma_f32_16x16x32_bf16(aT1, b0, accT[1][0], 0, 0, 0);
            accT[1][1] = __builtin_amdgcn_mfma_f32_16x16x32_bf16(aT1, bq, accT[1][1], 0, 0, 0);
            accS[0][0] = __builtin_amdgcn_mfma_f32_16x16x32_bf16(aS0, b0, accS[0][0], 0, 0, 0);
            accS[0][1] = __builtin_amdgcn_mfma_f32_16x16x32_bf16(aS0, bq, accS[0][1], 0, 0, 0);
            accS[1][0] = __builtin_amdgcn_mfma_f32_16x16x32_bf16(aS1, b0, accS[1][0], 0, 0, 0);
            accS[1][1] = __builtin_amdgcn_mfma_f32_16x16x32_bf16(aS1, bq, accS[1][1], 0, 0, 0);
        }
    }

    // LN1 partial sums
#pragma unroll
    for (int mi = 0; mi < 2; mi++)
#pragma unroll
        for (int r = 0; r < 4; r++) {
            float a0 = accS[mi][0][r], a1 = accS[mi][1][r];
            float ss = a0 + a1, qq = a0 * a0 + a1 * a1;
#pragma unroll
            for (int m = 1; m < 16; m <<= 1) {
                ss += __shfl_xor(ss, m, 64);
                qq += __shfl_xor(qq, m, 64);
            }
            if (col == 0) red[mi * 16 + quad * 4 + r][w] = make_float2(ss, qq);
        }
    __syncthreads();

    const float ga = g1[w * 32 + col],      ba = b1[w * 32 + col];
    const float gb = g1[w * 32 + 16 + col], bb = b1[w * 32 + 16 + col];
#pragma unroll
    for (int mi = 0; mi < 2; mi++)
#pragma unroll
        for (int r = 0; r < 4; r++) {
            int x = mi * 16 + quad * 4 + r;
            float2 p0 = red[x][0], p1 = red[x][1], p2 = red[x][2], p3 = red[x][3];
            float mean = (p0.x + p1.x + p2.x + p3.x) * (1.f / 128.f);
            float var  = (p0.y + p1.y + p2.y + p3.y) * (1.f / 128.f) - mean * mean;
            float rstd = rsqrtf(var + 1e-5f);
            int e0 = w * 32 + col, e1 = w * 32 + 16 + col;
            Xs[x * 136 + e0] = f2b((accS[mi][0][r] - mean) * rstd * ga + ba);
            Xs[x * 136 + e1] = f2b((accS[mi][1][r] - mean) * rstd * gb + bb);
            Vs[x * 136 + e0] = f2b(accT[mi][0][r]);
            Vs[x * 136 + e1] = f2b(accT[mi][1][r]);
        }
    __syncthreads();

    // phase B: QKV. Wave w -> heads 2w, 2w+1; token tiles j=0,1.
    short8 xb[2][4], xv[2][4];
#pragma unroll
    for (int j = 0; j < 2; j++)
#pragma unroll
        for (int kc = 0; kc < 4; kc++) {
            xb[j][kc] = *(const short8*)(Xs + (j * 16 + col) * 136 + kc * 32 + quad * 8);
            xv[j][kc] = *(const short8*)(Vs + (j * 16 + col) * 136 + kc * 32 + quad * 8);
        }
    f32x4 Q[2][2] = {}, K[2][2] = {}, V[2][2] = {};
#pragma unroll
    for (int hj = 0; hj < 2; hj++) {
        int h = 2 * w + hj;
#pragma unroll
        for (int kc = 0; kc < 4; kc++) {
            short8 aq = *(const short8*)(WQK + (size_t)(h * 16 + col) * 128 + kc * 32 + quad * 8);
            short8 ak = *(const short8*)(WQK + (size_t)(128 + h * 16 + col) * 128 + kc * 32 + quad * 8);
            short8 av = *(const short8*)(WV + (size_t)(h * 16 + col) * 128 + kc * 32 + quad * 8);
#pragma unroll
            for (int j = 0; j < 2; j++) {
                Q[hj][j] = __builtin_amdgcn_mfma_f32_16x16x32_bf16(aq, xb[j][kc], Q[hj][j], 0, 0, 0);
                K[hj][j] = __builtin_amdgcn_mfma_f32_16x16x32_bf16(ak, xb[j][kc], K[hj][j], 0, 0, 0);
                V[hj][j] = __builtin_amdgcn_mfma_f32_16x16x32_bf16(av, xv[j][kc], V[hj][j], 0, 0, 0);
            }
        }
    }
    ushort* VTs = At;   // dead after MFMA loop; [8 heads][16 d][stride 34]
#pragma unroll
    for (int hj = 0; hj < 2; hj++) {
        int h = 2 * w + hj;
#pragma unroll
        for (int j = 0; j < 2; j++) {
            int l = y * 32 + j * 16 + col;
            size_t base = ((size_t)(n * 8 + h) * 1024 + l) * 16 + quad * 4;
            union { unsigned u[2]; uint2 v; } oq, ok;
            oq.u[0] = pk2(Q[hj][j][0], Q[hj][j][1]); oq.u[1] = pk2(Q[hj][j][2], Q[hj][j][3]);
            ok.u[0] = pk2(K[hj][j][0], K[hj][j][1]); ok.u[1] = pk2(K[hj][j][2], K[hj][j][3]);
            *(uint2*)(Qh + base) = oq.v;
            *(uint2*)(Kh + base) = ok.v;
            int xp = ((col >> 2) << 3) + (j << 2) + (col & 3);
#pragma unroll
            for (int r = 0; r < 4; r++)
                VTs[(h * 16 + quad * 4 + r) * 34 + xp] = f2b(V[hj][j][r]);
        }
    }
#pragma unroll
    for (int k = 0; k < 2; k++) {
        int idx2 = t + k * 256;
        int r = idx2 >> 4, seg = idx2 & 15;
        *(uint4*)(TOKb + ((size_t)((y * 32 + r) * 25 + n)) * 128 + seg * 8) =
            *(const uint4*)(Vs + r * 136 + seg * 8);
    }
    __syncthreads();
    {   // coalesced VTg write
        int h = t >> 5, rem = t & 31, d = rem >> 1, xh = (rem & 1) * 16;
        size_t vrow = ((size_t)(n * 8 + h) * 32 + y) * 512;
        union { ushort u[8]; uint4 v; } o0, o1;
#pragma unroll
        for (int j = 0; j < 8; j++) {
            o0.u[j] = VTs[(h * 16 + d) * 34 + xh + j];
            o1.u[j] = VTs[(h * 16 + d) * 34 + xh + 8 + j];
        }
        *(uint4*)(VTg + vrow + d * 32 + xh)     = o0.v;
        *(uint4*)(VTg + vrow + d * 32 + xh + 8) = o1.v;
    }
}

// ---------------------------------------------------------------------------
// Attention + out_proj + residual + LN2 + FFN + conv. 512-thread blocks,
// grid 1600 (n,y,half). Wave w = head w (1 head/wave). Per-wave chain ~37
// MFMAs (was 74). No-max softmax, Ys on Rs, pk2 packs, deferred 1/sum.
// ---------------------------------------------------------------------------
__global__ __launch_bounds__(512)
void k_attn_ffn(
    const ushort* __restrict__ Qh, const ushort* __restrict__ Kh,
    const ushort* __restrict__ VTg, const ushort* __restrict__ WOP,
    const float* __restrict__ g2, const float* __restrict__ b2,
    const ushort* __restrict__ W1, const ushort* __restrict__ W2P,
    const ushort* __restrict__ WCP, const ushort* __restrict__ TOKb,
    float* __restrict__ out)
{
    __shared__ ushort OX[16 * 136];
    __shared__ ushort Rs[16 * 136];   // residual; later aliased as Ys
    __shared__ ushort Hs[16 * 264];
    __shared__ float2 red[16][8];
    ushort* Ys = Rs;                  // Rs dead 2 barriers before Ys write
    const int bid = blockIdx.x;                       // 1600 blocks
    const int idx = (bid & 7) * 200 + (bid >> 3);     // XCD-contiguous chunks
    const int n = idx / 64, rem = idx & 63;
    const int y = rem >> 1, half = rem & 1;
    const int l0 = y * 32 + half * 16;
    const int t = threadIdx.x, w = t >> 6, lane = t & 63;
    const int col = lane & 15, quad = lane >> 4;
    const int qx = half * 16 + col;

    {   // stage residual rows (16 tokens x 128 e, 512 thr x 4 ushorts)
        int r = t >> 5, seg = t & 31;
        *(uint2*)(Rs + r * 136 + seg * 4) =
            *(const uint2*)(TOKb + ((size_t)((l0 + r) * 25 + n)) * 128 + seg * 4);
    }

    // hoisted mask bits (head-independent)
    unsigned long long mbits = 0;
#pragma unroll
    for (int tt = 0; tt < 10; tt++) {
        int yy = y - 2 + (tt >> 1);
        bool rok = (yy >= 0) && (yy < 32);
        int kxb = ((tt & 1) << 4) + quad * 4;
#pragma unroll
        for (int r = 0; r < 4; r++) {
            int dd = kxb + r - qx;
            if (rok && ((unsigned)(dd + 2) <= 4u))
                mbits |= 1ull << (tt * 4 + r);
        }
    }

    short8 z8 = {0, 0, 0, 0, 0, 0, 0, 0};
    const size_t base = (size_t)(n * 8 + w) * 1024;        // head = w
    const size_t vbase = (size_t)(n * 8 + w) * 32 * 512;

    short8 qf = z8;
    if (quad < 2)
        qf = *(const short8*)(Qh + (base + y * 32 + half * 16 + col) * 16 + quad * 8);

    // scores (10 MFMAs)
    f32x4 Sc[10] = {};
#pragma unroll
    for (int tt = 0; tt < 10; tt++) {
        int kr = tt >> 1, kx = ((tt & 1) << 4) + col;
        int yyc = min(max(y - 2 + kr, 0), 31);
        short8 kf = z8;
        if (quad < 2)
            kf = *(const short8*)(Kh + (base + yyc * 32 + kx) * 16 + quad * 8);
        Sc[tt] = __builtin_amdgcn_mfma_f32_16x16x32_bf16(kf, qf, Sc[tt], 0, 0, 0);
    }

    // softmax WITHOUT max-subtraction (|S| ~ 0.05; shift-invariant)
    float sum = 0.f;
#pragma unroll
    for (int tt = 0; tt < 10; tt++)
#pragma unroll
        for (int r = 0; r < 4; r++) {
            bool ok = (mbits >> (tt * 4 + r)) & 1;
            float p = ok ? __expf(Sc[tt][r]) : 0.f;
            Sc[tt][r] = p;
            sum += p;
        }
    sum += __shfl_xor(sum, 16, 64);
    sum += __shfl_xor(sum, 32, 64);
    const float inv = 1.f / sum;

    // PV (5 MFMAs): A-frags from VTg; P packed UNNORMALIZED
    f32x4 O2 = {};
#pragma unroll
    for (int c = 0; c < 5; c++) {
        int yyc = min(max(y - 2 + c, 0), 31);
        short8 vt = *(const short8*)(VTg + vbase + (size_t)yyc * 512 + col * 32 + quad * 8);
        union { unsigned u[4]; short8 s; } pb;
        pb.u[0] = pk2(Sc[2 * c][0], Sc[2 * c][1]);
        pb.u[1] = pk2(Sc[2 * c][2], Sc[2 * c][3]);
        pb.u[2] = pk2(Sc[2 * c + 1][0], Sc[2 * c + 1][1]);
        pb.u[3] = pk2(Sc[2 * c + 1][2], Sc[2 * c + 1][3]);
        O2 = __builtin_amdgcn_mfma_f32_16x16x32_bf16(vt, pb.s, O2, 0, 0, 0);
    }
#pragma unroll
    for (int r = 0; r < 4; r++) O2[r] *= inv;

    // pack O (head w) -> OX: kpos = (w>>1)*32 + quad*8 + (w&1)*4 + r
    {
        union { unsigned u[2]; uint2 v; } pb;
        pb.u[0] = pk2(O2[0], O2[1]);
        pb.u[1] = pk2(O2[2], O2[3]);
        *(uint2*)(OX + col * 136 + (w >> 1) * 32 + quad * 8 + (w & 1) * 4) = pb.v;
    }
    __syncthreads();

    // out_proj: wave w -> e-tile w (4 MFMAs)
    f32x4 Y = {};
#pragma unroll
    for (int kc = 0; kc < 4; kc++) {
        short8 hb = *(const short8*)(OX + col * 136 + kc * 32 + quad * 8);
        short8 a = *(const short8*)(WOP + (size_t)(w * 16 + col) * 128 + kc * 32 + quad * 8);
        Y = __builtin_amdgcn_mfma_f32_16x16x32_bf16(a, hb, Y, 0, 0, 0);
    }
    // residual + LN2 partials (token = col)
    float s2 = 0.f, q2 = 0.f;
#pragma unroll
    for (int r = 0; r < 4; r++) {
        int e = w * 16 + quad * 4 + r;
        float v = Y[r] + b2f(Rs[col * 136 + e]);
        Y[r] = v;
        s2 += v; q2 += v * v;
    }
    s2 += __shfl_xor(s2, 16, 64); s2 += __shfl_xor(s2, 32, 64);
    q2 += __shfl_xor(q2, 16, 64); q2 += __shfl_xor(q2, 32, 64);
    if (quad == 0) red[col][w] = make_float2(s2, q2);
    __syncthreads();

    {
        float s = 0.f, q = 0.f;
#pragma unroll
        for (int j = 0; j < 8; j++) { s += red[col][j].x; q += red[col][j].y; }
        float mean = s * (1.f / 128.f);
        float var  = q * (1.f / 128.f) - mean * mean;
        float rstd = rsqrtf(var + 1e-5f);
#pragma unroll
        for (int r2 = 0; r2 < 4; r2 += 2) {
            int e = w * 16 + quad * 4 + r2;
            float v0 = (Y[r2]     - mean) * rstd * g2[e]     + b2[e];
            float v1 = (Y[r2 + 1] - mean) * rstd * g2[e + 1] + b2[e + 1];
            *(unsigned*)(OX + col * 136 + e) = pk2(v0, v1);
        }
    }
    __syncthreads();

    // ffn1: ft = 2w, 2w+1 (8 MFMAs)
    short8 xb[4];
#pragma unroll
    for (int kc = 0; kc < 4; kc++)
        xb[kc] = *(const short8*)(OX + col * 136 + kc * 32 + quad * 8);
    f32x4 H[2] = {};
#pragma unroll
    for (int jj = 0; jj < 2; jj++) {
        int ft = 2 * w + jj;
#pragma unroll
        for (int kc = 0; kc < 4; kc++) {
            short8 a = *(const short8*)(W1 + (size_t)(ft * 16 + col) * 128 + kc * 32 + quad * 8);
            H[jj] = __builtin_amdgcn_mfma_f32_16x16x32_bf16(a, xb[kc], H[jj], 0, 0, 0);
        }
    }
    // relu-pack: c = w, i = jj*4 + r  (matches W2P permutation)
    {
        union { unsigned u[4]; uint4 v; } pb;
        pb.u[0] = pk2(fmaxf(H[0][0], 0.f), fmaxf(H[0][1], 0.f));
        pb.u[1] = pk2(fmaxf(H[0][2], 0.f), fmaxf(H[0][3], 0.f));
        pb.u[2] = pk2(fmaxf(H[1][0], 0.f), fmaxf(H[1][1], 0.f));
        pb.u[3] = pk2(fmaxf(H[1][2], 0.f), fmaxf(H[1][3], 0.f));
        *(uint4*)(Hs + col * 264 + w * 32 + quad * 8) = pb.v;
    }
    __syncthreads();

    // ffn2: et = w over K=256 (8 MFMAs); residual from Y registers
    f32x4 Y2 = {};
#pragma unroll
    for (int kc = 0; kc < 8; kc++) {
        short8 hb = *(const short8*)(Hs + col * 264 + kc * 32 + quad * 8);
        short8 a = *(const short8*)(W2P + (size_t)(w * 16 + col) * 256 + kc * 32 + quad * 8);
        Y2 = __builtin_amdgcn_mfma_f32_16x16x32_bf16(a, hb, Y2, 0, 0, 0);
    }
    // Ys pack: kpos = (w>>1)*32 + quad*8 + (w&1)*4 + r
    {
        union { unsigned u[2]; uint2 v; } pb;
        pb.u[0] = pk2(Y2[0] + Y[0], Y2[1] + Y[1]);
        pb.u[1] = pk2(Y2[2] + Y[2], Y2[3] + Y[3]);
        *(uint2*)(Ys + col * 136 + (w >> 1) * 32 + quad * 8 + (w & 1) * 4) = pb.v;
    }
    __syncthreads();

    // conv: waves 0..3 -> ot = w (4 MFMAs)
    if (w < 4) {
        f32x4 O = {};
#pragma unroll
        for (int c = 0; c < 4; c++) {
            short8 yb = *(const short8*)(Ys + col * 136 + c * 32 + quad * 8);
            short8 a = *(const short8*)(WCP + (size_t)(w * 16 + col) * 128 + c * 32 + quad * 8);
            O = __builtin_amdgcn_mfma_f32_16x16x32_bf16(a, yb, O, 0, 0, 0);
        }
        const int l = l0 + col;
#pragma unroll
        for (int r2 = 0; r2 < 4; r2++) {
            int o = w * 16 + quad * 4 + r2;
            out[(size_t)(o * 25 + n) * 1024 + l] = O[r2];
        }
    }
}

// ---------------------------------------------------------------------------
// Launch
// ---------------------------------------------------------------------------
extern "C" void kernel_launch(void* const* d_in, const int* in_sizes, int n_in,
                              void* d_out, int out_size, void* d_ws, size_t ws_size,
                              hipStream_t stream)
{
    const float* buffer   = (const float*)d_in[0];
    const float* spa      = (const float*)d_in[1];
    const float* w_mlp    = (const float*)d_in[2];
    const float* ln1_g    = (const float*)d_in[3];
    const float* ln1_b    = (const float*)d_in[4];
    const float* in_proj  = (const float*)d_in[5];
    const float* out_proj = (const float*)d_in[6];
    const float* ln2_g    = (const float*)d_in[7];
    const float* ln2_b    = (const float*)d_in[8];
    const float* ff_w1    = (const float*)d_in[9];
    const float* ff_w2    = (const float*)d_in[10];
    const float* conv_w   = (const float*)d_in[11];
    float* out = (float*)d_out;

    char* ws = (char*)d_ws;
    ushort* TOKb = (ushort*)(ws);                //  6,553,600 residual bf16
    ushort* Qh   = (ushort*)(ws + 6553600);      //  6,553,600 [n][h][l][d]
    ushort* Kh   = (ushort*)(ws + 13107200);     //  6,553,600
    ushort* VTg  = (ushort*)(ws + 19660800);     //  6,553,600 [n][h][y][d][xp]
    ushort* Wb   = (ushort*)(ws + 26214400);     //    425,984

    k_prep<<<dim3((W_TOTAL + 255) / 256), 256, 0, stream>>>(
        w_mlp, in_proj, out_proj, ff_w1, ff_w2, conv_w, Wb);
    k_tok_qkv<<<dim3(800), 256, 0, stream>>>(buffer, spa, Wb + OFF_W2,
                                             Wb + OFF_WQK, Wb + OFF_WV,
                                             ln1_g, ln1_b, TOKb, Qh, Kh, VTg);
    k_attn_ffn<<<dim3(1600), 512, 0, stream>>>(Qh, Kh, VTg, Wb + OFF_WO,
                                               ln2_g, ln2_b, Wb + OFF_W1,
                                               Wb + OFF_W2F, Wb + OFF_WC,
                                               TOKb, out);
}